// Round 4
// baseline (782.709 us; speedup 1.0000x reference)
//
#include <hip/hip_runtime.h>

typedef __attribute__((ext_vector_type(8))) short s8v;
typedef __attribute__((ext_vector_type(4))) float f4;

#define SEQ 1024
#define BATCH 2048

// Split (a,b) into a bf16 hi-plane word and bf16 lo-plane (residual) word.
// Word layout: low16 = a's bf16, high16 = b's bf16. Pure bit ops (truncation
// split) — no dependence on cvt_pk operand order or rounding mode.
__device__ __forceinline__ void splitpk(float a, float b, unsigned &hw, unsigned &lw) {
  unsigned au = __float_as_uint(a), bu = __float_as_uint(b);
  hw = (au >> 16) | (bu & 0xffff0000u);
  float la = a - __uint_as_float(au & 0xffff0000u);
  float lb = b - __uint_as_float(bu & 0xffff0000u);
  lw = (__float_as_uint(la) >> 16) | (__float_as_uint(lb) & 0xffff0000u);
}

__device__ __forceinline__ f4 MF(const unsigned (&a)[4], const unsigned (&b)[4], f4 c) {
  union U { unsigned u[4]; s8v v; } A, B;
  A.u[0] = a[0]; A.u[1] = a[1]; A.u[2] = a[2]; A.u[3] = a[3];
  B.u[0] = b[0]; B.u[1] = b[1]; B.u[2] = b[2]; B.u[3] = b[3];
  return __builtin_amdgcn_mfma_f32_16x16x32_bf16(A.v, B.v, c, 0, 0, 0);
}

// k-map convention (applied identically to A and B operands so any mismatch
// with the true HW map cancels): element i of lane-group g sits at
//   k = 4*g + i          for i in [0,4)
//   k = 16 + 4*g + (i-4) for i in [4,8)
// C-layout (row = 4g + reg) therefore feeds the next B-fragment with NO
// cross-lane movement.

__device__ __forceinline__ void conv(f4 va, f4 vb, unsigned (&hi)[4], unsigned (&lo)[4]) {
  splitpk(va[0], va[1], hi[0], lo[0]);
  splitpk(va[2], va[3], hi[1], lo[1]);
  splitpk(vb[0], vb[1], hi[2], lo[2]);
  splitpk(vb[2], vb[3], hi[3], lo[3]);
}

__device__ __forceinline__ void loadA(const float* W, int row, int g,
                                      unsigned (&hi)[4], unsigned (&lo)[4]) {
  const float* p = W + row * 32;
  f4 u = *(const f4*)(p + 4 * g);
  f4 v = *(const f4*)(p + 16 + 4 * g);
  splitpk(u[0], u[1], hi[0], lo[0]);
  splitpk(u[2], u[3], hi[1], lo[1]);
  splitpk(v[0], v[1], hi[2], lo[2]);
  splitpk(v[2], v[3], hi[3], lo[3]);
}

__global__ __launch_bounds__(64) void rnn_fused(
    const float* __restrict__ x,    const float* __restrict__ h0,
    const float* __restrict__ Wih0, const float* __restrict__ Whh0,
    const float* __restrict__ bih0, const float* __restrict__ bhh0,
    const float* __restrict__ Wih1, const float* __restrict__ Whh1,
    const float* __restrict__ bih1, const float* __restrict__ bhh1,
    const float* __restrict__ Wout, const float* __restrict__ boutp,
    float* __restrict__ out)
{
  const int lane = threadIdx.x;
  const int c = lane & 15;      // batch column within tile (also A-frag row)
  const int g = lane >> 4;      // lane group 0..3
  // Two independent batch tiles per wave: the second stream exists purely to
  // fill the first stream's MFMA<->VALU hazard/latency slots.
  const int bb[2] = { (int)blockIdx.x * 32 + c, (int)blockIdx.x * 32 + 16 + c };

  // Weight A-fragments (hi/lo split), SHARED between the two tiles.
  unsigned W00h[4], W00l[4], W01h[4], W01l[4];
  unsigned Wi10h[4], Wi10l[4], Wi11h[4], Wi11l[4];
  unsigned Wh10h[4], Wh10l[4], Wh11h[4], Wh11l[4];
  loadA(Whh0, c,      g, W00h,  W00l);
  loadA(Whh0, 16 + c, g, W01h,  W01l);
  loadA(Wih1, c,      g, Wi10h, Wi10l);
  loadA(Wih1, 16 + c, g, Wi11h, Wi11l);
  loadA(Whh1, c,      g, Wh10h, Wh10l);
  loadA(Whh1, 16 + c, g, Wh11h, Wh11l);

  // Output-projection A-fragment: Wout broadcast to every row, so
  // D[row][col] = out[col] for every row — no cross-lane reduction needed.
  unsigned WOh[4], WOl[4];
  {
    f4 u = *(const f4*)(Wout + 4 * g);
    f4 v = *(const f4*)(Wout + 16 + 4 * g);
    splitpk(u[0], u[1], WOh[0], WOl[0]);
    splitpk(u[2], u[3], WOh[1], WOl[1]);
    splitpk(v[0], v[1], WOh[2], WOl[2]);
    splitpk(v[2], v[3], WOh[3], WOl[3]);
  }

  // Hidden-state B-fragments (col = c), hi/lo split, per tile.
  unsigned B1h[2][4], B1l[2][4], B2h[2][4], B2l[2][4];
#pragma unroll
  for (int u = 0; u < 2; ++u) {
    const float* p1 = h0 + bb[u] * 32;
    f4 a0 = *(const f4*)(p1 + 4 * g);
    f4 a1 = *(const f4*)(p1 + 16 + 4 * g);
    splitpk(a0[0], a0[1], B1h[u][0], B1l[u][0]);
    splitpk(a0[2], a0[3], B1h[u][1], B1l[u][1]);
    splitpk(a1[0], a1[1], B1h[u][2], B1l[u][2]);
    splitpk(a1[2], a1[3], B1h[u][3], B1l[u][3]);
    const float* p2 = p1 + BATCH * 32;
    f4 c0 = *(const f4*)(p2 + 4 * g);
    f4 c1 = *(const f4*)(p2 + 16 + 4 * g);
    splitpk(c0[0], c0[1], B2h[u][0], B2l[u][0]);
    splitpk(c0[2], c0[3], B2h[u][1], B2l[u][1]);
    splitpk(c1[0], c1[1], B2h[u][2], B2l[u][2]);
    splitpk(c1[2], c1[3], B2h[u][3], B2l[u][3]);
  }

  // Per-lane row constants (C-layout rows: set0 = 4g+r, set1 = 16+4g+r), fp32.
  f4 wih0A, wih0B, b0A, b0B, b1A, b1B;
#pragma unroll
  for (int r = 0; r < 4; ++r) {
    int j0 = 4 * g + r, j1 = 16 + 4 * g + r;
    wih0A[r] = Wih0[j0];              wih0B[r] = Wih0[j1];
    b0A[r]   = bih0[j0] + bhh0[j0];   b0B[r]   = bih0[j1] + bhh0[j1];
    b1A[r]   = bih1[j0] + bhh1[j0];   b1B[r]   = bih1[j1] + bhh1[j1];
  }
  const float bO = boutp[0];
  const f4 z = {0.f, 0.f, 0.f, 0.f};

  f4 v10[2], v11[2], v20[2], v21[2];  // last step's relu outputs (f32, C layout)

  // One timestep for BOTH tiles, phase-interleaved. Identical arithmetic to
  // the verified R1 kernel (chained-C MFMAs, sequential L0 -> L1 -> out).
  auto STEP = [&](int T, float X0, float X1) {
    const float XV[2] = { X0, X1 };
    // ---- layer 0: h1n = relu(x*Wih0 + b0 + Whh0 @ h1) ----
    f4 c00[2], c01[2];
#pragma unroll
    for (int u = 0; u < 2; ++u) {
#pragma unroll
      for (int r = 0; r < 4; ++r) {
        c00[u][r] = fmaf(XV[u], wih0A[r], b0A[r]);
        c01[u][r] = fmaf(XV[u], wih0B[r], b0B[r]);
      }
    }
#pragma unroll
    for (int u = 0; u < 2; ++u) {
      c00[u] = MF(W00h, B1h[u], c00[u]);
      c01[u] = MF(W01h, B1h[u], c01[u]);
      c00[u] = MF(W00h, B1l[u], c00[u]);
      c01[u] = MF(W01h, B1l[u], c01[u]);
      c00[u] = MF(W00l, B1h[u], c00[u]);
      c01[u] = MF(W01l, B1h[u], c01[u]);
    }
#pragma unroll
    for (int u = 0; u < 2; ++u) {
#pragma unroll
      for (int r = 0; r < 4; ++r) {
        v10[u][r] = fmaxf(c00[u][r], 0.f);
        v11[u][r] = fmaxf(c01[u][r], 0.f);
      }
      conv(v10[u], v11[u], B1h[u], B1l[u]);   // h1n -> B fragment (in place)
    }

    // ---- layer 1: h2n = relu(Wih1 @ h1n + b1 + Whh1 @ h2) ----
    f4 cA0[2], cA1[2], cB0[2], cB1[2];
#pragma unroll
    for (int u = 0; u < 2; ++u) {
      cA0[u] = MF(Wi10h, B1h[u], b1A);
      cA1[u] = MF(Wi11h, B1h[u], b1B);
      cB0[u] = MF(Wh10h, B2h[u], z);
      cB1[u] = MF(Wh11h, B2h[u], z);
      cA0[u] = MF(Wi10h, B1l[u], cA0[u]);
      cA1[u] = MF(Wi11h, B1l[u], cA1[u]);
      cB0[u] = MF(Wh10h, B2l[u], cB0[u]);
      cB1[u] = MF(Wh11h, B2l[u], cB1[u]);
      cA0[u] = MF(Wi10l, B1h[u], cA0[u]);
      cA1[u] = MF(Wi11l, B1h[u], cA1[u]);
      cB0[u] = MF(Wh10l, B2h[u], cB0[u]);
      cB1[u] = MF(Wh11l, B2h[u], cB1[u]);
    }
#pragma unroll
    for (int u = 0; u < 2; ++u) {
#pragma unroll
      for (int r = 0; r < 4; ++r) {
        v20[u][r] = fmaxf(cA0[u][r] + cB0[u][r], 0.f);
        v21[u][r] = fmaxf(cA1[u][r] + cB1[u][r], 0.f);
      }
      conv(v20[u], v21[u], B2h[u], B2l[u]);   // h2n -> B fragment (in place)
    }

    // ---- output: out[t,b] = dot(Wout, h2n) + b_out, via broadcast-A MFMA ----
#pragma unroll
    for (int u = 0; u < 2; ++u) {
      f4 cO = MF(WOh, B2h[u], z);
      cO = MF(WOh, B2l[u], cO);
      cO = MF(WOl, B2h[u], cO);
      if (g == 0) out[T * BATCH + bb[u]] = cO[0] + bO;
    }
  };

  // x prefetch depth 4 (index clamped so the tail loads stay in-bounds)
  float xa[2], xb[2], xc[2], xd[2];
#pragma unroll
  for (int u = 0; u < 2; ++u) {
    xa[u] = x[0 * BATCH + bb[u]];
    xb[u] = x[1 * BATCH + bb[u]];
    xc[u] = x[2 * BATCH + bb[u]];
    xd[u] = x[3 * BATCH + bb[u]];
  }

#pragma unroll 1
  for (int t = 0; t < SEQ; t += 4) {
    STEP(t + 0, xa[0], xa[1]);
    { int ti = (t + 4 < SEQ) ? t + 4 : SEQ - 1; xa[0] = x[ti * BATCH + bb[0]]; xa[1] = x[ti * BATCH + bb[1]]; }
    STEP(t + 1, xb[0], xb[1]);
    { int ti = (t + 5 < SEQ) ? t + 5 : SEQ - 1; xb[0] = x[ti * BATCH + bb[0]]; xb[1] = x[ti * BATCH + bb[1]]; }
    STEP(t + 2, xc[0], xc[1]);
    { int ti = (t + 6 < SEQ) ? t + 6 : SEQ - 1; xc[0] = x[ti * BATCH + bb[0]]; xc[1] = x[ti * BATCH + bb[1]]; }
    STEP(t + 3, xd[0], xd[1]);
    { int ti = (t + 7 < SEQ) ? t + 7 : SEQ - 1; xd[0] = x[ti * BATCH + bb[0]]; xd[1] = x[ti * BATCH + bb[1]]; }
  }

  // final hidden state (f32 values from the last step, C layout rows)
  float* hs = out + SEQ * BATCH;
#pragma unroll
  for (int u = 0; u < 2; ++u) {
    *(f4*)(hs + bb[u] * 32 + 4 * g)                    = v10[u];
    *(f4*)(hs + bb[u] * 32 + 16 + 4 * g)               = v11[u];
    *(f4*)(hs + BATCH * 32 + bb[u] * 32 + 4 * g)       = v20[u];
    *(f4*)(hs + BATCH * 32 + bb[u] * 32 + 16 + 4 * g)  = v21[u];
  }
}

extern "C" void kernel_launch(void* const* d_in, const int* in_sizes, int n_in,
                              void* d_out, int out_size, void* d_ws, size_t ws_size,
                              hipStream_t stream) {
  rnn_fused<<<dim3(64), dim3(64), 0, stream>>>(
      (const float*)d_in[0],  (const float*)d_in[1],  (const float*)d_in[2],
      (const float*)d_in[3],  (const float*)d_in[4],  (const float*)d_in[5],
      (const float*)d_in[6],  (const float*)d_in[7],  (const float*)d_in[8],
      (const float*)d_in[9],  (const float*)d_in[10], (const float*)d_in[11],
      (float*)d_out);
}

// Round 5
// 278.791 us; speedup vs baseline: 2.8075x; 2.8075x over previous
//
#include <hip/hip_runtime.h>

typedef __attribute__((ext_vector_type(8))) short s8v;
typedef __attribute__((ext_vector_type(4))) float f4;
typedef __attribute__((ext_vector_type(4))) unsigned u4v;
typedef __attribute__((ext_vector_type(2))) unsigned u2v;

#define SEQ 1024
#define BATCH 2048

// Split (a,b) into a bf16 hi-plane word and bf16 lo-plane (residual) word.
// Word layout: low16 = a's bf16, high16 = b's bf16. Pure bit ops.
__device__ __forceinline__ void splitpk(float a, float b, unsigned &hw, unsigned &lw) {
  unsigned au = __float_as_uint(a), bu = __float_as_uint(b);
  hw = (au >> 16) | (bu & 0xffff0000u);
  float la = a - __uint_as_float(au & 0xffff0000u);
  float lb = b - __uint_as_float(bu & 0xffff0000u);
  lw = (__float_as_uint(la) >> 16) | (__float_as_uint(lb) & 0xffff0000u);
}

__device__ __forceinline__ f4 MF(const unsigned (&a)[4], const unsigned (&b)[4], f4 c) {
  union U { unsigned u[4]; s8v v; } A, B;
  A.u[0] = a[0]; A.u[1] = a[1]; A.u[2] = a[2]; A.u[3] = a[3];
  B.u[0] = b[0]; B.u[1] = b[1]; B.u[2] = b[2]; B.u[3] = b[3];
  return __builtin_amdgcn_mfma_f32_16x16x32_bf16(A.v, B.v, c, 0, 0, 0);
}

// k-map (same on A and B operands, so any mismatch with the true HW map
// cancels): elem i of lane-group g -> k = 4g+i (i<4), k = 16+4g+(i-4) (i>=4).
// C-layout (row = 4g + reg) therefore feeds the next B-fragment with NO
// cross-lane movement; word w of B-frag = pack of two consecutive C regs.

__device__ __forceinline__ void conv(f4 va, f4 vb, unsigned (&hi)[4], unsigned (&lo)[4]) {
  splitpk(va[0], va[1], hi[0], lo[0]);
  splitpk(va[2], va[3], hi[1], lo[1]);
  splitpk(vb[0], vb[1], hi[2], lo[2]);
  splitpk(vb[2], vb[3], hi[3], lo[3]);
}

__device__ __forceinline__ void loadA(const float* W, int row, int g,
                                      unsigned (&hi)[4], unsigned (&lo)[4]) {
  const float* p = W + row * 32;
  f4 u = *(const f4*)(p + 4 * g);
  f4 v = *(const f4*)(p + 16 + 4 * g);
  splitpk(u[0], u[1], hi[0], lo[0]);
  splitpk(u[2], u[3], hi[1], lo[1]);
  splitpk(v[0], v[1], hi[2], lo[2]);
  splitpk(v[2], v[3], hi[3], lo[3]);
}

// 4-wave-specialized pipeline per 16-batch tile:
//   wave 0 (A) : layer 0, step s          (6 MFMA)  -> H1[(s+1)&1]
//   wave 1 (B0): layer 1 rows 0-15, t=s-1 (6 MFMA)  -> H2[s&1] words 0,1
//   wave 2 (B1): layer 1 rows 16-31,t=s-1 (6 MFMA)  -> H2[s&1] words 2,3
//   wave 3 (C) : out-proj, t=s-2          (3 MFMA)  -> out[t]
// One __syncthreads() per slot; double-buffered LDS; skew absorbs deps.
__global__ __launch_bounds__(256) void rnn_fused(
    const float* __restrict__ x,    const float* __restrict__ h0,
    const float* __restrict__ Wih0, const float* __restrict__ Whh0,
    const float* __restrict__ bih0, const float* __restrict__ bhh0,
    const float* __restrict__ Wih1, const float* __restrict__ Whh1,
    const float* __restrict__ bih1, const float* __restrict__ bhh1,
    const float* __restrict__ Wout, const float* __restrict__ boutp,
    float* __restrict__ out)
{
  const int tid  = threadIdx.x;
  const int wid  = tid >> 6;
  const int lane = tid & 63;
  const int c = lane & 15;      // batch column within tile (also A-frag row)
  const int g = lane >> 4;      // lane group 0..3
  const int b = blockIdx.x * 16 + c;
  const unsigned li = (unsigned)lane * 4u;   // u32 index of this lane's b128 slot

  // [parity][hi/lo plane][lane*4 + word]
  __shared__ unsigned LH1[2][2][256];
  __shared__ unsigned LH2[2][2][256];

  const f4 z = {0.f, 0.f, 0.f, 0.f};
  float* hs = out + SEQ * BATCH;

  if (wid == 0) {
    // ================= WAVE A : layer 0 =================
    unsigned W00h[4], W00l[4], W01h[4], W01l[4];
    loadA(Whh0, c,      g, W00h, W00l);
    loadA(Whh0, 16 + c, g, W01h, W01l);
    f4 wih0A, wih0B, b0A, b0B;
#pragma unroll
    for (int r = 0; r < 4; ++r) {
      int j0 = 4 * g + r, j1 = 16 + 4 * g + r;
      wih0A[r] = Wih0[j0];            wih0B[r] = Wih0[j1];
      b0A[r]   = bih0[j0] + bhh0[j0]; b0B[r]   = bih0[j1] + bhh0[j1];
    }
    unsigned B1h[4], B1l[4];
    {
      const float* p1 = h0 + b * 32;
      f4 u = *(const f4*)(p1 + 4 * g);
      f4 v = *(const f4*)(p1 + 16 + 4 * g);
      splitpk(u[0], u[1], B1h[0], B1l[0]);
      splitpk(u[2], u[3], B1h[1], B1l[1]);
      splitpk(v[0], v[1], B1h[2], B1l[2]);
      splitpk(v[2], v[3], B1h[3], B1l[3]);
    }
    f4 v10 = z, v11 = z;
    float xa = x[0 * BATCH + b];
    float xb = x[1 * BATCH + b];
    float xc2 = x[2 * BATCH + b];

#pragma unroll 1
    for (int s = 0; s < SEQ + 2; ++s) {
      if (s < SEQ) {
        float XV = xa; xa = xb; xb = xc2;
        { int ti = (s + 3 < SEQ) ? s + 3 : SEQ - 1; xc2 = x[ti * BATCH + b]; }
        f4 c00, c01;
#pragma unroll
        for (int r = 0; r < 4; ++r) {
          c00[r] = fmaf(XV, wih0A[r], b0A[r]);
          c01[r] = fmaf(XV, wih0B[r], b0B[r]);
        }
        c00 = MF(W00h, B1h, c00);  c01 = MF(W01h, B1h, c01);
        c00 = MF(W00h, B1l, c00);  c01 = MF(W01h, B1l, c01);
        c00 = MF(W00l, B1h, c00);  c01 = MF(W01l, B1h, c01);
#pragma unroll
        for (int r = 0; r < 4; ++r) {
          v10[r] = fmaxf(c00[r], 0.f);
          v11[r] = fmaxf(c01[r], 0.f);
        }
        conv(v10, v11, B1h, B1l);           // h1_{s+1} -> frags (also kept in regs)
        int p = (s + 1) & 1;
        u4v wh = { B1h[0], B1h[1], B1h[2], B1h[3] };
        u4v wl = { B1l[0], B1l[1], B1l[2], B1l[3] };
        *(u4v*)&LH1[p][0][li] = wh;
        *(u4v*)&LH1[p][1][li] = wl;
      }
      __syncthreads();
    }
    *(f4*)(hs + b * 32 + 4 * g)      = v10;   // h1_SEQ
    *(f4*)(hs + b * 32 + 16 + 4 * g) = v11;

  } else if (wid == 1 || wid == 2) {
    // ============ WAVES B0/B1 : layer 1, row half ============
    const int half = wid - 1;                  // 0: rows 0-15, 1: rows 16-31
    unsigned WiH[4], WiL[4], WhH[4], WhL[4];
    loadA(Wih1, half * 16 + c, g, WiH, WiL);
    loadA(Whh1, half * 16 + c, g, WhH, WhL);
    f4 b1;
#pragma unroll
    for (int r = 0; r < 4; ++r) {
      int j = half * 16 + 4 * g + r;
      b1[r] = bih1[j] + bhh1[j];
    }
    // init h2_0 words (this half) into H2[0]
    {
      f4 hh = *(const f4*)(h0 + BATCH * 32 + b * 32 + half * 16 + 4 * g);
      unsigned h0w, l0w, h1w, l1w;
      splitpk(hh[0], hh[1], h0w, l0w);
      splitpk(hh[2], hh[3], h1w, l1w);
      u2v wh = { h0w, h1w }, wl = { l0w, l1w };
      *(u2v*)&LH2[0][0][li + 2u * half] = wh;
      *(u2v*)&LH2[0][1][li + 2u * half] = wl;
    }
    f4 v2 = z;

#pragma unroll 1
    for (int s = 0; s < SEQ + 2; ++s) {
      if (s >= 1 && s <= SEQ) {
        u4v t1h = *(const u4v*)&LH1[s & 1][0][li];
        u4v t1l = *(const u4v*)&LH1[s & 1][1][li];
        u4v t2h = *(const u4v*)&LH2[(s + 1) & 1][0][li];
        u4v t2l = *(const u4v*)&LH2[(s + 1) & 1][1][li];
        unsigned B1h[4] = { t1h[0], t1h[1], t1h[2], t1h[3] };
        unsigned B1l[4] = { t1l[0], t1l[1], t1l[2], t1l[3] };
        unsigned B2h[4] = { t2h[0], t2h[1], t2h[2], t2h[3] };
        unsigned B2l[4] = { t2l[0], t2l[1], t2l[2], t2l[3] };
        f4 a0 = MF(WiH, B1h, b1);  a0 = MF(WhH, B2h, a0);
        f4 a1 = MF(WiH, B1l, z);   a1 = MF(WhH, B2l, a1);
        f4 a2 = MF(WiL, B1h, z);   a2 = MF(WhL, B2h, a2);
#pragma unroll
        for (int r = 0; r < 4; ++r)
          v2[r] = fmaxf(a0[r] + a1[r] + a2[r], 0.f);
        unsigned hw0, lw0, hw1, lw1;
        splitpk(v2[0], v2[1], hw0, lw0);
        splitpk(v2[2], v2[3], hw1, lw1);
        u2v wh = { hw0, hw1 }, wl = { lw0, lw1 };
        *(u2v*)&LH2[s & 1][0][li + 2u * half] = wh;
        *(u2v*)&LH2[s & 1][1][li + 2u * half] = wl;
      }
      __syncthreads();
    }
    *(f4*)(hs + BATCH * 32 + b * 32 + half * 16 + 4 * g) = v2;  // h2_SEQ half

  } else {
    // ================= WAVE C : output projection =================
    unsigned WOh[4], WOl[4];
    {
      f4 u = *(const f4*)(Wout + 4 * g);
      f4 v = *(const f4*)(Wout + 16 + 4 * g);
      splitpk(u[0], u[1], WOh[0], WOl[0]);
      splitpk(u[2], u[3], WOh[1], WOl[1]);
      splitpk(v[0], v[1], WOh[2], WOl[2]);
      splitpk(v[2], v[3], WOh[3], WOl[3]);
    }
    const float bO = boutp[0];

#pragma unroll 1
    for (int s = 0; s < SEQ + 2; ++s) {
      if (s >= 2) {
        u4v t2h = *(const u4v*)&LH2[(s + 1) & 1][0][li];
        u4v t2l = *(const u4v*)&LH2[(s + 1) & 1][1][li];
        unsigned B2h[4] = { t2h[0], t2h[1], t2h[2], t2h[3] };
        unsigned B2l[4] = { t2l[0], t2l[1], t2l[2], t2l[3] };
        f4 cO = MF(WOh, B2h, z);
        cO = MF(WOh, B2l, cO);
        cO = MF(WOl, B2h, cO);
        if (g == 0) out[(s - 2) * BATCH + b] = cO[0] + bO;
      }
      __syncthreads();
    }
  }
}

extern "C" void kernel_launch(void* const* d_in, const int* in_sizes, int n_in,
                              void* d_out, int out_size, void* d_ws, size_t ws_size,
                              hipStream_t stream) {
  rnn_fused<<<dim3(128), dim3(256), 0, stream>>>(
      (const float*)d_in[0],  (const float*)d_in[1],  (const float*)d_in[2],
      (const float*)d_in[3],  (const float*)d_in[4],  (const float*)d_in[5],
      (const float*)d_in[6],  (const float*)d_in[7],  (const float*)d_in[8],
      (const float*)d_in[9],  (const float*)d_in[10], (const float*)d_in[11],
      (float*)d_out);
}

// Round 6
// 253.649 us; speedup vs baseline: 3.0858x; 1.0991x over previous
//
#include <hip/hip_runtime.h>

typedef __attribute__((ext_vector_type(8))) short s8v;
typedef __attribute__((ext_vector_type(4))) float f4;
typedef __attribute__((ext_vector_type(4))) unsigned u4v;

#define SEQ 1024
#define BATCH 2048

// Split (a,b) into a bf16 hi-plane word and bf16 lo-plane (residual) word.
// Word layout: low16 = a's bf16, high16 = b's bf16. Pure bit ops.
__device__ __forceinline__ void splitpk(float a, float b, unsigned &hw, unsigned &lw) {
  unsigned au = __float_as_uint(a), bu = __float_as_uint(b);
  hw = (au >> 16) | (bu & 0xffff0000u);
  float la = a - __uint_as_float(au & 0xffff0000u);
  float lb = b - __uint_as_float(bu & 0xffff0000u);
  lw = (__float_as_uint(la) >> 16) | (__float_as_uint(lb) & 0xffff0000u);
}

__device__ __forceinline__ f4 MF(const unsigned (&a)[4], const unsigned (&b)[4], f4 c) {
  union U { unsigned u[4]; s8v v; } A, B;
  A.u[0] = a[0]; A.u[1] = a[1]; A.u[2] = a[2]; A.u[3] = a[3];
  B.u[0] = b[0]; B.u[1] = b[1]; B.u[2] = b[2]; B.u[3] = b[3];
  return __builtin_amdgcn_mfma_f32_16x16x32_bf16(A.v, B.v, c, 0, 0, 0);
}

// k-map (same on A and B operands so any mismatch with the true HW map
// cancels): elem i of lane-group g -> k = 4g+i (i<4), k = 16+4g+(i-4) (i>=4).
// C-layout (row = 4g + reg) feeds the next B-fragment with NO cross-lane moves.

__device__ __forceinline__ void conv(f4 va, f4 vb, unsigned (&hi)[4], unsigned (&lo)[4]) {
  splitpk(va[0], va[1], hi[0], lo[0]);
  splitpk(va[2], va[3], hi[1], lo[1]);
  splitpk(vb[0], vb[1], hi[2], lo[2]);
  splitpk(vb[2], vb[3], hi[3], lo[3]);
}

__device__ __forceinline__ void loadA(const float* W, int row, int g,
                                      unsigned (&hi)[4], unsigned (&lo)[4]) {
  const float* p = W + row * 32;
  f4 u = *(const f4*)(p + 4 * g);
  f4 v = *(const f4*)(p + 16 + 4 * g);
  splitpk(u[0], u[1], hi[0], lo[0]);
  splitpk(u[2], u[3], hi[1], lo[1]);
  splitpk(v[0], v[1], hi[2], lo[2]);
  splitpk(v[2], v[3], hi[3], lo[3]);
}

// 4-wave feed-forward pipeline, 2 timesteps per slot, 1 barrier per slot.
//   wave 0 (A): h1 recurrence (in regs)          -> LH1[m&1]
//   wave 1 (D): P = Wih1@h1 + b1 (feed-forward)  -> LP [m&1]
//   wave 2 (B): h2 = relu(P + Whh1@h2) (in regs) -> LB2[m&1]
//   wave 3 (C): out = Wout.h2 + bO
// Skews: A slots [0,511], D [1,512], B [2,513], C [3,514].
__global__ __launch_bounds__(256) void rnn_fused(
    const float* __restrict__ x,    const float* __restrict__ h0,
    const float* __restrict__ Wih0, const float* __restrict__ Whh0,
    const float* __restrict__ bih0, const float* __restrict__ bhh0,
    const float* __restrict__ Wih1, const float* __restrict__ Whh1,
    const float* __restrict__ bih1, const float* __restrict__ bhh1,
    const float* __restrict__ Wout, const float* __restrict__ boutp,
    float* __restrict__ out)
{
  const int tid  = threadIdx.x;
  const int wid  = tid >> 6;
  const int lane = tid & 63;
  const int c = lane & 15;      // batch column within tile (also A-frag row)
  const int g = lane >> 4;      // lane group 0..3
  const int b = blockIdx.x * 16 + c;
  const unsigned li = (unsigned)lane * 4u;

  __shared__ unsigned LH1[2][2][2][256];  // [parity][step j][plane][u32]
  __shared__ float    LP [2][2][512];     // [parity][step j][lane*8 + 0..7]
  __shared__ unsigned LB2[2][2][2][256];  // [parity][step j][plane][u32]

  const f4 z = {0.f, 0.f, 0.f, 0.f};
  float* hs = out + SEQ * BATCH;
  const int NSLOT = SEQ / 2 + 3;          // 515

  if (wid == 0) {
    // ================= WAVE A : layer 0 (h1 recurrence) =================
    unsigned W00h[4], W00l[4], W01h[4], W01l[4];
    loadA(Whh0, c,      g, W00h, W00l);
    loadA(Whh0, 16 + c, g, W01h, W01l);
    f4 wih0A, wih0B, b0A, b0B;
#pragma unroll
    for (int r = 0; r < 4; ++r) {
      int j0 = 4 * g + r, j1 = 16 + 4 * g + r;
      wih0A[r] = Wih0[j0];            wih0B[r] = Wih0[j1];
      b0A[r]   = bih0[j0] + bhh0[j0]; b0B[r]   = bih0[j1] + bhh0[j1];
    }
    unsigned B1h[4], B1l[4];
    {
      const float* p1 = h0 + b * 32;
      f4 u = *(const f4*)(p1 + 4 * g);
      f4 v = *(const f4*)(p1 + 16 + 4 * g);
      splitpk(u[0], u[1], B1h[0], B1l[0]);
      splitpk(u[2], u[3], B1h[1], B1l[1]);
      splitpk(v[0], v[1], B1h[2], B1l[2]);
      splitpk(v[2], v[3], B1h[3], B1l[3]);
    }
    f4 v10 = z, v11 = z;
    float xc0 = x[0 * BATCH + b];
    float xc1 = x[1 * BATCH + b];

#pragma unroll 1
    for (int m = 0; m < NSLOT; ++m) {
      if (m < SEQ / 2) {
        int n0 = 2 * m + 2, n1 = 2 * m + 3;
        float xn0 = x[(n0 < SEQ ? n0 : SEQ - 1) * BATCH + b];
        float xn1 = x[(n1 < SEQ ? n1 : SEQ - 1) * BATCH + b];
#pragma unroll
        for (int j = 0; j < 2; ++j) {
          float XV = j ? xc1 : xc0;
          f4 c00, c01;
#pragma unroll
          for (int r = 0; r < 4; ++r) {
            c00[r] = fmaf(XV, wih0A[r], b0A[r]);
            c01[r] = fmaf(XV, wih0B[r], b0B[r]);
          }
          c00 = MF(W00h, B1h, c00);  c01 = MF(W01h, B1h, c01);
          c00 = MF(W00h, B1l, c00);  c01 = MF(W01h, B1l, c01);
          c00 = MF(W00l, B1h, c00);  c01 = MF(W01l, B1h, c01);
#pragma unroll
          for (int r = 0; r < 4; ++r) {
            v10[r] = fmaxf(c00[r], 0.f);
            v11[r] = fmaxf(c01[r], 0.f);
          }
          conv(v10, v11, B1h, B1l);
          u4v wh = { B1h[0], B1h[1], B1h[2], B1h[3] };
          u4v wl = { B1l[0], B1l[1], B1l[2], B1l[3] };
          *(u4v*)&LH1[m & 1][j][0][li] = wh;
          *(u4v*)&LH1[m & 1][j][1][li] = wl;
        }
        xc0 = xn0; xc1 = xn1;
      }
      __syncthreads();
    }
    *(f4*)(hs + b * 32 + 4 * g)      = v10;   // h1_SEQ
    *(f4*)(hs + b * 32 + 16 + 4 * g) = v11;

  } else if (wid == 1) {
    // ========== WAVE D : feeder P = Wih1 @ h1 + b1 (full 32 rows) ==========
    unsigned WiH0[4], WiL0[4], WiH1[4], WiL1[4];
    loadA(Wih1, c,      g, WiH0, WiL0);
    loadA(Wih1, 16 + c, g, WiH1, WiL1);
    f4 b1A, b1B;
#pragma unroll
    for (int r = 0; r < 4; ++r) {
      int j0 = 4 * g + r, j1 = 16 + 4 * g + r;
      b1A[r] = bih1[j0] + bhh1[j0];
      b1B[r] = bih1[j1] + bhh1[j1];
    }

#pragma unroll 1
    for (int m = 0; m < NSLOT; ++m) {
      if (m >= 1 && m <= SEQ / 2) {
        int p = (m - 1) & 1;
        u4v f0h = *(const u4v*)&LH1[p][0][0][li];
        u4v f0l = *(const u4v*)&LH1[p][0][1][li];
        u4v f1h = *(const u4v*)&LH1[p][1][0][li];
        u4v f1l = *(const u4v*)&LH1[p][1][1][li];
#pragma unroll
        for (int j = 0; j < 2; ++j) {
          unsigned B1h[4] = { j ? f1h[0] : f0h[0], j ? f1h[1] : f0h[1],
                              j ? f1h[2] : f0h[2], j ? f1h[3] : f0h[3] };
          unsigned B1l[4] = { j ? f1l[0] : f0l[0], j ? f1l[1] : f0l[1],
                              j ? f1l[2] : f0l[2], j ? f1l[3] : f0l[3] };
          f4 p0 = MF(WiH0, B1h, b1A);
          f4 p1 = MF(WiH0, B1l, z);
          f4 p2 = MF(WiL0, B1h, z);
          f4 q0 = MF(WiH1, B1h, b1B);
          f4 q1 = MF(WiH1, B1l, z);
          f4 q2 = MF(WiL1, B1h, z);
          f4 P0, P1;
#pragma unroll
          for (int r = 0; r < 4; ++r) {
            P0[r] = p0[r] + p1[r] + p2[r];
            P1[r] = q0[r] + q1[r] + q2[r];
          }
          *(f4*)&LP[m & 1][j][lane * 8]     = P0;
          *(f4*)&LP[m & 1][j][lane * 8 + 4] = P1;
        }
      }
      __syncthreads();
    }

  } else if (wid == 2) {
    // ========== WAVE B : h2 recurrence = relu(P + Whh1 @ h2) ==========
    unsigned WhH0[4], WhL0[4], WhH1[4], WhL1[4];
    loadA(Whh1, c,      g, WhH0, WhL0);
    loadA(Whh1, 16 + c, g, WhH1, WhL1);
    unsigned B2h[4], B2l[4];
    f4 v20 = z, v21 = z;
    {
      const float* p2 = h0 + BATCH * 32 + b * 32;
      f4 u = *(const f4*)(p2 + 4 * g);
      f4 v = *(const f4*)(p2 + 16 + 4 * g);
      splitpk(u[0], u[1], B2h[0], B2l[0]);
      splitpk(u[2], u[3], B2h[1], B2l[1]);
      splitpk(v[0], v[1], B2h[2], B2l[2]);
      splitpk(v[2], v[3], B2h[3], B2l[3]);
      v20 = u; v21 = v;
    }

#pragma unroll 1
    for (int m = 0; m < NSLOT; ++m) {
      if (m >= 2 && m <= SEQ / 2 + 1) {
        int p = (m - 1) & 1;
        f4 P00 = *(const f4*)&LP[p][0][lane * 8];
        f4 P01 = *(const f4*)&LP[p][0][lane * 8 + 4];
        f4 P10 = *(const f4*)&LP[p][1][lane * 8];
        f4 P11 = *(const f4*)&LP[p][1][lane * 8 + 4];
#pragma unroll
        for (int j = 0; j < 2; ++j) {
          f4 r0 = MF(WhH0, B2h, j ? P10 : P00);
          f4 r1 = MF(WhH0, B2l, z);
          f4 r2 = MF(WhL0, B2h, z);
          f4 s0 = MF(WhH1, B2h, j ? P11 : P01);
          f4 s1 = MF(WhH1, B2l, z);
          f4 s2 = MF(WhL1, B2h, z);
#pragma unroll
          for (int r = 0; r < 4; ++r) {
            v20[r] = fmaxf(r0[r] + r1[r] + r2[r], 0.f);
            v21[r] = fmaxf(s0[r] + s1[r] + s2[r], 0.f);
          }
          conv(v20, v21, B2h, B2l);
          u4v wh = { B2h[0], B2h[1], B2h[2], B2h[3] };
          u4v wl = { B2l[0], B2l[1], B2l[2], B2l[3] };
          *(u4v*)&LB2[m & 1][j][0][li] = wh;
          *(u4v*)&LB2[m & 1][j][1][li] = wl;
        }
      }
      __syncthreads();
    }
    *(f4*)(hs + BATCH * 32 + b * 32 + 4 * g)      = v20;  // h2_SEQ
    *(f4*)(hs + BATCH * 32 + b * 32 + 16 + 4 * g) = v21;

  } else {
    // ================= WAVE C : output projection =================
    unsigned WOh[4], WOl[4];
    {
      f4 u = *(const f4*)(Wout + 4 * g);
      f4 v = *(const f4*)(Wout + 16 + 4 * g);
      splitpk(u[0], u[1], WOh[0], WOl[0]);
      splitpk(u[2], u[3], WOh[1], WOl[1]);
      splitpk(v[0], v[1], WOh[2], WOl[2]);
      splitpk(v[2], v[3], WOh[3], WOl[3]);
    }
    const float bO = boutp[0];

#pragma unroll 1
    for (int m = 0; m < NSLOT; ++m) {
      if (m >= 3) {
        int p = (m - 1) & 1;
#pragma unroll
        for (int j = 0; j < 2; ++j) {
          u4v th = *(const u4v*)&LB2[p][j][0][li];
          u4v tl = *(const u4v*)&LB2[p][j][1][li];
          unsigned B2h[4] = { th[0], th[1], th[2], th[3] };
          unsigned B2l[4] = { tl[0], tl[1], tl[2], tl[3] };
          f4 cO = MF(WOh, B2h, z);
          cO = MF(WOh, B2l, cO);
          cO = MF(WOl, B2h, cO);
          int t = 2 * (m - 3) + j;
          if (g == 0) out[t * BATCH + b] = cO[0] + bO;
        }
      }
      __syncthreads();
    }
  }
}

extern "C" void kernel_launch(void* const* d_in, const int* in_sizes, int n_in,
                              void* d_out, int out_size, void* d_ws, size_t ws_size,
                              hipStream_t stream) {
  rnn_fused<<<dim3(128), dim3(256), 0, stream>>>(
      (const float*)d_in[0],  (const float*)d_in[1],  (const float*)d_in[2],
      (const float*)d_in[3],  (const float*)d_in[4],  (const float*)d_in[5],
      (const float*)d_in[6],  (const float*)d_in[7],  (const float*)d_in[8],
      (const float*)d_in[9],  (const float*)d_in[10], (const float*)d_in[11],
      (float*)d_out);
}

// Round 7
// 237.858 us; speedup vs baseline: 3.2907x; 1.0664x over previous
//
#include <hip/hip_runtime.h>

typedef __attribute__((ext_vector_type(8))) short s8v;
typedef __attribute__((ext_vector_type(4))) float f4;
typedef __attribute__((ext_vector_type(4))) unsigned u4v;

#define SEQ 1024
#define BATCH 2048
#define SLOT 4
#define NSLOT (SEQ / SLOT + 3)   // 259

// Split (a,b) into a bf16 hi-plane word and bf16 lo-plane (residual) word.
// Word layout: low16 = a's bf16, high16 = b's bf16. Pure bit ops.
__device__ __forceinline__ void splitpk(float a, float b, unsigned &hw, unsigned &lw) {
  unsigned au = __float_as_uint(a), bu = __float_as_uint(b);
  hw = (au >> 16) | (bu & 0xffff0000u);
  float la = a - __uint_as_float(au & 0xffff0000u);
  float lb = b - __uint_as_float(bu & 0xffff0000u);
  lw = (__float_as_uint(la) >> 16) | (__float_as_uint(lb) & 0xffff0000u);
}

__device__ __forceinline__ f4 MF(const unsigned (&a)[4], const unsigned (&b)[4], f4 c) {
  union U { unsigned u[4]; s8v v; } A, B;
  A.u[0] = a[0]; A.u[1] = a[1]; A.u[2] = a[2]; A.u[3] = a[3];
  B.u[0] = b[0]; B.u[1] = b[1]; B.u[2] = b[2]; B.u[3] = b[3];
  return __builtin_amdgcn_mfma_f32_16x16x32_bf16(A.v, B.v, c, 0, 0, 0);
}

// k-map (same on A and B operands so any mismatch with the true HW map
// cancels): elem i of lane-group g -> k = 4g+i (i<4), k = 16+4g+(i-4) (i>=4).
// C-layout (row = 4g + reg) feeds the next B-fragment with NO cross-lane moves.

__device__ __forceinline__ void conv(f4 va, f4 vb, unsigned (&hi)[4], unsigned (&lo)[4]) {
  splitpk(va[0], va[1], hi[0], lo[0]);
  splitpk(va[2], va[3], hi[1], lo[1]);
  splitpk(vb[0], vb[1], hi[2], lo[2]);
  splitpk(vb[2], vb[3], hi[3], lo[3]);
}

__device__ __forceinline__ void loadA(const float* W, int row, int g,
                                      unsigned (&hi)[4], unsigned (&lo)[4]) {
  const float* p = W + row * 32;
  f4 u = *(const f4*)(p + 4 * g);
  f4 v = *(const f4*)(p + 16 + 4 * g);
  splitpk(u[0], u[1], hi[0], lo[0]);
  splitpk(u[2], u[3], hi[1], lo[1]);
  splitpk(v[0], v[1], hi[2], lo[2]);
  splitpk(v[2], v[3], hi[3], lo[3]);
}

// 4-wave feed-forward pipeline, 4 timesteps per slot, 1 barrier per slot.
//   wave 0 (A): h1 recurrence (in regs)          -> LH1[m&1]
//   wave 1 (D): P = Wih1@h1 + b1 (feed-forward)  -> LP [m&1]
//   wave 2 (B): h2 = relu(P + Whh1@h2) (in regs) -> LB2[m&1]
//   wave 3 (C): out = Wout.h2 + bO
// Skews: A slots [0,255], D [1,256], B [2,257], C [3,258].
__global__ __launch_bounds__(256) void rnn_fused(
    const float* __restrict__ x,    const float* __restrict__ h0,
    const float* __restrict__ Wih0, const float* __restrict__ Whh0,
    const float* __restrict__ bih0, const float* __restrict__ bhh0,
    const float* __restrict__ Wih1, const float* __restrict__ Whh1,
    const float* __restrict__ bih1, const float* __restrict__ bhh1,
    const float* __restrict__ Wout, const float* __restrict__ boutp,
    float* __restrict__ out)
{
  const int tid  = threadIdx.x;
  const int wid  = tid >> 6;
  const int lane = tid & 63;
  const int c = lane & 15;      // batch column within tile (also A-frag row)
  const int g = lane >> 4;      // lane group 0..3
  const int b = blockIdx.x * 16 + c;
  const unsigned li = (unsigned)lane * 4u;

  // All planes are b128-per-lane at lane*16B — the conflict-minimal pattern.
  __shared__ unsigned LH1[2][SLOT][2][256];  // [parity][step j][hi/lo][u32]
  __shared__ float    LP [2][SLOT][2][256];  // [parity][step j][P0/P1][f32]
  __shared__ unsigned LB2[2][SLOT][2][256];  // [parity][step j][hi/lo][u32]

  const f4 z = {0.f, 0.f, 0.f, 0.f};
  float* hs = out + SEQ * BATCH;

  if (wid == 0) {
    // ================= WAVE A : layer 0 (h1 recurrence) =================
    unsigned W00h[4], W00l[4], W01h[4], W01l[4];
    loadA(Whh0, c,      g, W00h, W00l);
    loadA(Whh0, 16 + c, g, W01h, W01l);
    f4 wih0A, wih0B, b0A, b0B;
#pragma unroll
    for (int r = 0; r < 4; ++r) {
      int j0 = 4 * g + r, j1 = 16 + 4 * g + r;
      wih0A[r] = Wih0[j0];            wih0B[r] = Wih0[j1];
      b0A[r]   = bih0[j0] + bhh0[j0]; b0B[r]   = bih0[j1] + bhh0[j1];
    }
    unsigned B1h[4], B1l[4];
    {
      const float* p1 = h0 + b * 32;
      f4 u = *(const f4*)(p1 + 4 * g);
      f4 v = *(const f4*)(p1 + 16 + 4 * g);
      splitpk(u[0], u[1], B1h[0], B1l[0]);
      splitpk(u[2], u[3], B1h[1], B1l[1]);
      splitpk(v[0], v[1], B1h[2], B1l[2]);
      splitpk(v[2], v[3], B1h[3], B1l[3]);
    }
    f4 v10 = z, v11 = z;
    float xc[SLOT];
#pragma unroll
    for (int j = 0; j < SLOT; ++j) xc[j] = x[j * BATCH + b];

#pragma unroll 1
    for (int m = 0; m < NSLOT; ++m) {
      if (m < SEQ / SLOT) {
        float xn[SLOT];
#pragma unroll
        for (int j = 0; j < SLOT; ++j) {
          int ti = SLOT * m + SLOT + j;
          xn[j] = x[(ti < SEQ ? ti : SEQ - 1) * BATCH + b];
        }
#pragma unroll
        for (int j = 0; j < SLOT; ++j) {
          float XV = xc[j];
          f4 c00, c01;
#pragma unroll
          for (int r = 0; r < 4; ++r) {
            c00[r] = fmaf(XV, wih0A[r], b0A[r]);
            c01[r] = fmaf(XV, wih0B[r], b0B[r]);
          }
          c00 = MF(W00h, B1h, c00);  c01 = MF(W01h, B1h, c01);
          c00 = MF(W00h, B1l, c00);  c01 = MF(W01h, B1l, c01);
          c00 = MF(W00l, B1h, c00);  c01 = MF(W01l, B1h, c01);
#pragma unroll
          for (int r = 0; r < 4; ++r) {
            v10[r] = fmaxf(c00[r], 0.f);
            v11[r] = fmaxf(c01[r], 0.f);
          }
          conv(v10, v11, B1h, B1l);
          u4v wh = { B1h[0], B1h[1], B1h[2], B1h[3] };
          u4v wl = { B1l[0], B1l[1], B1l[2], B1l[3] };
          *(u4v*)&LH1[m & 1][j][0][li] = wh;
          *(u4v*)&LH1[m & 1][j][1][li] = wl;
        }
#pragma unroll
        for (int j = 0; j < SLOT; ++j) xc[j] = xn[j];
      }
      __syncthreads();
    }
    *(f4*)(hs + b * 32 + 4 * g)      = v10;   // h1_SEQ
    *(f4*)(hs + b * 32 + 16 + 4 * g) = v11;

  } else if (wid == 1) {
    // ========== WAVE D : feeder P = Wih1 @ h1 + b1 (full 32 rows) ==========
    unsigned WiH0[4], WiL0[4], WiH1[4], WiL1[4];
    loadA(Wih1, c,      g, WiH0, WiL0);
    loadA(Wih1, 16 + c, g, WiH1, WiL1);
    f4 b1A, b1B;
#pragma unroll
    for (int r = 0; r < 4; ++r) {
      int j0 = 4 * g + r, j1 = 16 + 4 * g + r;
      b1A[r] = bih1[j0] + bhh1[j0];
      b1B[r] = bih1[j1] + bhh1[j1];
    }

#pragma unroll 1
    for (int m = 0; m < NSLOT; ++m) {
      if (m >= 1 && m <= SEQ / SLOT) {
        int p = (m - 1) & 1;
        u4v fh[SLOT], fl[SLOT];
#pragma unroll
        for (int j = 0; j < SLOT; ++j) {
          fh[j] = *(const u4v*)&LH1[p][j][0][li];
          fl[j] = *(const u4v*)&LH1[p][j][1][li];
        }
#pragma unroll
        for (int j = 0; j < SLOT; ++j) {
          unsigned B1h[4] = { fh[j][0], fh[j][1], fh[j][2], fh[j][3] };
          unsigned B1l[4] = { fl[j][0], fl[j][1], fl[j][2], fl[j][3] };
          f4 p0 = MF(WiH0, B1h, b1A);
          f4 p1 = MF(WiH0, B1l, z);
          f4 p2 = MF(WiL0, B1h, z);
          f4 q0 = MF(WiH1, B1h, b1B);
          f4 q1 = MF(WiH1, B1l, z);
          f4 q2 = MF(WiL1, B1h, z);
          f4 P0, P1;
#pragma unroll
          for (int r = 0; r < 4; ++r) {
            P0[r] = p0[r] + p1[r] + p2[r];
            P1[r] = q0[r] + q1[r] + q2[r];
          }
          *(f4*)&LP[m & 1][j][0][li] = P0;
          *(f4*)&LP[m & 1][j][1][li] = P1;
        }
      }
      __syncthreads();
    }

  } else if (wid == 2) {
    // ========== WAVE B : h2 recurrence = relu(P + Whh1 @ h2) ==========
    unsigned WhH0[4], WhL0[4], WhH1[4], WhL1[4];
    loadA(Whh1, c,      g, WhH0, WhL0);
    loadA(Whh1, 16 + c, g, WhH1, WhL1);
    unsigned B2h[4], B2l[4];
    f4 v20 = z, v21 = z;
    {
      const float* p2 = h0 + BATCH * 32 + b * 32;
      f4 u = *(const f4*)(p2 + 4 * g);
      f4 v = *(const f4*)(p2 + 16 + 4 * g);
      splitpk(u[0], u[1], B2h[0], B2l[0]);
      splitpk(u[2], u[3], B2h[1], B2l[1]);
      splitpk(v[0], v[1], B2h[2], B2l[2]);
      splitpk(v[2], v[3], B2h[3], B2l[3]);
      v20 = u; v21 = v;
    }

#pragma unroll 1
    for (int m = 0; m < NSLOT; ++m) {
      if (m >= 2 && m <= SEQ / SLOT + 1) {
        int p = (m - 1) & 1;
        f4 Pa[SLOT], Pb[SLOT];
#pragma unroll
        for (int j = 0; j < SLOT; ++j) {
          Pa[j] = *(const f4*)&LP[p][j][0][li];
          Pb[j] = *(const f4*)&LP[p][j][1][li];
        }
#pragma unroll
        for (int j = 0; j < SLOT; ++j) {
          f4 r0 = MF(WhH0, B2h, Pa[j]);
          f4 r1 = MF(WhH0, B2l, z);
          f4 r2 = MF(WhL0, B2h, z);
          f4 s0 = MF(WhH1, B2h, Pb[j]);
          f4 s1 = MF(WhH1, B2l, z);
          f4 s2 = MF(WhL1, B2h, z);
#pragma unroll
          for (int r = 0; r < 4; ++r) {
            v20[r] = fmaxf(r0[r] + r1[r] + r2[r], 0.f);
            v21[r] = fmaxf(s0[r] + s1[r] + s2[r], 0.f);
          }
          conv(v20, v21, B2h, B2l);
          u4v wh = { B2h[0], B2h[1], B2h[2], B2h[3] };
          u4v wl = { B2l[0], B2l[1], B2l[2], B2l[3] };
          *(u4v*)&LB2[m & 1][j][0][li] = wh;
          *(u4v*)&LB2[m & 1][j][1][li] = wl;
        }
      }
      __syncthreads();
    }
    *(f4*)(hs + BATCH * 32 + b * 32 + 4 * g)      = v20;  // h2_SEQ
    *(f4*)(hs + BATCH * 32 + b * 32 + 16 + 4 * g) = v21;

  } else {
    // ================= WAVE C : output projection =================
    unsigned WOh[4], WOl[4];
    {
      f4 u = *(const f4*)(Wout + 4 * g);
      f4 v = *(const f4*)(Wout + 16 + 4 * g);
      splitpk(u[0], u[1], WOh[0], WOl[0]);
      splitpk(u[2], u[3], WOh[1], WOl[1]);
      splitpk(v[0], v[1], WOh[2], WOl[2]);
      splitpk(v[2], v[3], WOh[3], WOl[3]);
    }
    const float bO = boutp[0];

#pragma unroll 1
    for (int m = 0; m < NSLOT; ++m) {
      if (m >= 3) {
        int p = (m - 1) & 1;
        u4v th[SLOT], tl[SLOT];
#pragma unroll
        for (int j = 0; j < SLOT; ++j) {
          th[j] = *(const u4v*)&LB2[p][j][0][li];
          tl[j] = *(const u4v*)&LB2[p][j][1][li];
        }
#pragma unroll
        for (int j = 0; j < SLOT; ++j) {
          unsigned B2h[4] = { th[j][0], th[j][1], th[j][2], th[j][3] };
          unsigned B2l[4] = { tl[j][0], tl[j][1], tl[j][2], tl[j][3] };
          f4 cO = MF(WOh, B2h, z);
          cO = MF(WOh, B2l, cO);
          cO = MF(WOl, B2h, cO);
          int t = SLOT * (m - 3) + j;
          if (g == 0) out[t * BATCH + b] = cO[0] + bO;
        }
      }
      __syncthreads();
    }
  }
}

extern "C" void kernel_launch(void* const* d_in, const int* in_sizes, int n_in,
                              void* d_out, int out_size, void* d_ws, size_t ws_size,
                              hipStream_t stream) {
  rnn_fused<<<dim3(128), dim3(256), 0, stream>>>(
      (const float*)d_in[0],  (const float*)d_in[1],  (const float*)d_in[2],
      (const float*)d_in[3],  (const float*)d_in[4],  (const float*)d_in[5],
      (const float*)d_in[6],  (const float*)d_in[7],  (const float*)d_in[8],
      (const float*)d_in[9],  (const float*)d_in[10], (const float*)d_in[11],
      (float*)d_out);
}